// Round 3
// baseline (373.406 us; speedup 1.0000x reference)
//
#include <hip/hip_runtime.h>
#include <hip/hip_bf16.h>

typedef unsigned short u16;
typedef __attribute__((ext_vector_type(8))) short short8;
typedef __attribute__((ext_vector_type(4))) float f32x4;

__device__ __forceinline__ float silu_f(float x) { return x / (1.0f + __expf(-x)); }
__device__ __forceinline__ float softplus_f(float x) {
    return (x > 20.0f) ? x : log1pf(__expf(x));
}

// Block 0: wqk[j]=sum_i Wq[i][j]*Wk[i], u1[j]=sum_i W1[j][i]*Wv[i], bqk=bq.Wk
// Blocks 1..16: W2 -> bf16 copy
// Blocks 17..: zero asum
__global__ __launch_bounds__(256) void prep_kernel(
    const float* __restrict__ Wq, const float* __restrict__ bq,
    const float* __restrict__ Wk, const float* __restrict__ Wv,
    const float* __restrict__ W1, const float* __restrict__ W2,
    float* __restrict__ wqk, float* __restrict__ u1, float* __restrict__ bqk,
    u16* __restrict__ W2bf, float* __restrict__ asum, int G)
{
    const int tid = threadIdx.x;
    const int bid = blockIdx.x;
    if (bid == 0) {
        __shared__ float sm[128];
        if (tid < 128) {
            float acc = 0.f;
            #pragma unroll 8
            for (int i = 0; i < 128; ++i) acc += Wq[i * 128 + tid] * Wk[i];
            wqk[tid] = acc;
            sm[tid] = bq[tid] * Wk[tid];
        } else {
            const int j = tid - 128;
            float acc = 0.f;
            #pragma unroll 8
            for (int i = 0; i < 128; ++i) acc += W1[j * 128 + i] * Wv[i];
            u1[j] = acc;
        }
        __syncthreads();
        if (tid == 0) {
            float s = 0.f;
            for (int i = 0; i < 128; ++i) s += sm[i];
            bqk[0] = s;
        }
    } else if (bid <= 16) {
        const int base = (bid - 1) * 1024 + tid * 4;
        const float4 w = *reinterpret_cast<const float4*>(W2 + base);
        const float f[4] = {w.x, w.y, w.z, w.w};
        u16 o[4];
        #pragma unroll
        for (int e = 0; e < 4; ++e) {
            __hip_bfloat16 hb = __float2bfloat16(f[e]);
            __builtin_memcpy(&o[e], &hb, 2);
        }
        *reinterpret_cast<ushort4*>(W2bf + base) = make_ushort4(o[0], o[1], o[2], o[3]);
    } else {
        const int i = (bid - 17) * 256 + tid;
        if (i < G) asum[i] = 0.f;
    }
}

// One 32-lane half-wave per node: dot = ns[n,:].wqk, attn = softplus(dot*ratio*scale)
__global__ __launch_bounds__(256) void attn_kernel(
    const float* __restrict__ ns, const int* __restrict__ batch,
    const float* __restrict__ spin, const float* __restrict__ wqk,
    const float* __restrict__ bqk, float* __restrict__ attn,
    float* __restrict__ asum, int N)
{
    const int lane = threadIdx.x & 63;
    const int w = threadIdx.x >> 6;
    const int half = lane >> 5;
    const int l32 = lane & 31;
    const int n = blockIdx.x * 8 + w * 2 + half;
    if (n >= N) return;
    const float4 nsv = *reinterpret_cast<const float4*>(ns + (size_t)n * 128 + l32 * 4);
    const float4 wv  = *reinterpret_cast<const float4*>(wqk + l32 * 4);
    float p = nsv.x * wv.x + nsv.y * wv.y + nsv.z * wv.z + nsv.w * wv.w;
    #pragma unroll
    for (int off = 16; off > 0; off >>= 1) p += __shfl_xor(p, off, 64);
    if (l32 == 0) {
        const int g = batch[n];
        const float sp = spin[g];
        const float ratio = sp / fmaxf(sp, 1.0f);
        const float xx = (p + bqk[0]) * ratio * 0.08838834764831845f;
        const float a = softplus_f(xx);
        attn[n] = a;
        atomicAdd(&asum[g], a);
    }
}

// 64 nodes per block. c + h1 (bf16) in LDS, then per-wave 16x128 MFMA GEMM
// against L1-resident W2bf, fused epilogue out = ns + c*Wv + silu(acc+b2).
__global__ __launch_bounds__(256) void main_kernel(
    const float* __restrict__ ns, const int* __restrict__ batch,
    const float* __restrict__ spin, const float* __restrict__ Wv,
    const float* __restrict__ b1, const float* __restrict__ b2,
    const float* __restrict__ u1, const float* __restrict__ attn,
    const float* __restrict__ asum, const u16* __restrict__ W2bf,
    float* __restrict__ out, int N)
{
    __shared__ float c_lds[64];
    __shared__ __align__(16) u16 h1[64][136];   // pad 128->136 (272B rows) vs bank conflicts
    const int tid = threadIdx.x;
    const int n0 = blockIdx.x * 64;

    if (tid < 64) {
        const int n = n0 + tid;
        float c = 0.f;
        if (n < N) {
            const int g = batch[n];
            c = attn[n] * spin[g] / asum[g];
        }
        c_lds[tid] = c;
    }
    __syncthreads();

    // h1[node][j] = silu(c[node]*u1[j] + b1[j]), bf16. Thread: 4 j's x 8 nodes.
    {
        const int j0 = (tid & 31) * 4;
        const int nb = (tid >> 5) * 8;
        const float4 u1v = *reinterpret_cast<const float4*>(u1 + j0);
        const float4 b1v = *reinterpret_cast<const float4*>(b1 + j0);
        const float uu[4] = {u1v.x, u1v.y, u1v.z, u1v.w};
        const float bb[4] = {b1v.x, b1v.y, b1v.z, b1v.w};
        #pragma unroll
        for (int e = 0; e < 8; ++e) {
            const int node = nb + e;
            const float c = c_lds[node];
            u16 pk[4];
            #pragma unroll
            for (int q = 0; q < 4; ++q) {
                const float hv = silu_f(c * uu[q] + bb[q]);
                __hip_bfloat16 hb = __float2bfloat16(hv);
                __builtin_memcpy(&pk[q], &hb, 2);
            }
            *reinterpret_cast<ushort4*>(&h1[node][j0]) =
                make_ushort4(pk[0], pk[1], pk[2], pk[3]);
        }
    }
    __syncthreads();

    const int lane = tid & 63;
    const int w = tid >> 6;
    const int r16 = lane & 15;
    const int g4 = lane >> 4;
    const int nw0 = w * 16;   // wave's 16-node sub-tile

    // A-frags: lane holds h1[row = r16][k = kt*32 + g4*8 + e]
    short8 a[4];
    const u16* arow = &h1[nw0 + r16][g4 * 8];
    #pragma unroll
    for (int kt = 0; kt < 4; ++kt)
        a[kt] = *reinterpret_cast<const short8*>(arow + kt * 32);

    #pragma unroll
    for (int ct = 0; ct < 8; ++ct) {
        const int i = ct * 16 + r16;
        const u16* brow = W2bf + i * 128 + g4 * 8;   // B[k][col=i] = W2[i][k]
        f32x4 acc = {0.f, 0.f, 0.f, 0.f};
        #pragma unroll
        for (int kt = 0; kt < 4; ++kt) {
            const short8 b = *reinterpret_cast<const short8*>(brow + kt * 32);
            acc = __builtin_amdgcn_mfma_f32_16x16x32_bf16(a[kt], b, acc, 0, 0, 0);
        }
        const float b2i = b2[i];
        const float wvi = Wv[i];
        #pragma unroll
        for (int r = 0; r < 4; ++r) {
            const int nl = nw0 + g4 * 4 + r;          // D: row=(lane>>4)*4+reg, col=lane&15
            const int n = n0 + nl;
            if (n < N) {
                const float h2v = silu_f(acc[r] + b2i);
                out[(size_t)n * 128 + i] = ns[(size_t)n * 128 + i] + c_lds[nl] * wvi + h2v;
            }
        }
    }
}

extern "C" void kernel_launch(void* const* d_in, const int* in_sizes, int n_in,
                              void* d_out, int out_size, void* d_ws, size_t ws_size,
                              hipStream_t stream) {
    (void)n_in; (void)out_size; (void)ws_size;
    const float* ns    = (const float*)d_in[0];
    const int*   batch = (const int*)d_in[1];
    const float* spin  = (const float*)d_in[2];
    const float* Wq    = (const float*)d_in[3];
    const float* bq    = (const float*)d_in[4];
    const float* Wk    = (const float*)d_in[5];
    const float* Wv    = (const float*)d_in[6];
    const float* W1    = (const float*)d_in[7];
    const float* b1    = (const float*)d_in[8];
    const float* W2    = (const float*)d_in[9];
    const float* b2    = (const float*)d_in[10];
    float* out = (float*)d_out;

    const int N = in_sizes[0] / 128;
    const int G = in_sizes[2];

    float* ws = (float*)d_ws;
    size_t o = 0;
    float* asum = ws + o; o += (size_t)((G + 63) & ~63);
    float* attn = ws + o; o += (size_t)((N + 63) & ~63);
    float* wqk  = ws + o; o += 128;
    float* u1   = ws + o; o += 128;
    float* bqk  = ws + o; o += 64;
    u16*   W2bf = (u16*)(ws + o);   // 16384 u16 = 32 KB

    const int zeroBlocks = (G + 255) / 256;
    prep_kernel<<<dim3(17 + zeroBlocks), dim3(256), 0, stream>>>(
        Wq, bq, Wk, Wv, W1, W2, wqk, u1, bqk, W2bf, asum, G);
    attn_kernel<<<dim3((N + 7) / 8), dim3(256), 0, stream>>>(
        ns, batch, spin, wqk, bqk, attn, asum, N);
    main_kernel<<<dim3((N + 63) / 64), dim3(256), 0, stream>>>(
        ns, batch, spin, Wv, b1, b2, u1, attn, asum, W2bf, out, N);
}

// Round 4
// 295.595 us; speedup vs baseline: 1.2632x; 1.2632x over previous
//
#include <hip/hip_runtime.h>
#include <hip/hip_bf16.h>

typedef unsigned short u16;
typedef __attribute__((ext_vector_type(8))) short short8;
typedef __attribute__((ext_vector_type(4))) float f32x4;

__device__ __forceinline__ float silu_f(float x) { return x / (1.0f + __expf(-x)); }
__device__ __forceinline__ float softplus_f(float x) {
    return (x > 20.0f) ? x : log1pf(__expf(x));
}

// Block 0: wqk[j]=sum_i Wq[i][j]*Wk[i], u1[j]=sum_i W1[j][i]*Wv[i], bqk=bq.Wk
// Blocks 1..16: W2 -> bf16 copy
// Blocks 17..: zero asum
__global__ __launch_bounds__(256) void prep_kernel(
    const float* __restrict__ Wq, const float* __restrict__ bq,
    const float* __restrict__ Wk, const float* __restrict__ Wv,
    const float* __restrict__ W1, const float* __restrict__ W2,
    float* __restrict__ wqk, float* __restrict__ u1, float* __restrict__ bqk,
    u16* __restrict__ W2bf, float* __restrict__ asum, int G)
{
    const int tid = threadIdx.x;
    const int bid = blockIdx.x;
    if (bid == 0) {
        __shared__ float sm[128];
        if (tid < 128) {
            float acc = 0.f;
            #pragma unroll 8
            for (int i = 0; i < 128; ++i) acc += Wq[i * 128 + tid] * Wk[i];
            wqk[tid] = acc;
            sm[tid] = bq[tid] * Wk[tid];
        } else {
            const int j = tid - 128;
            float acc = 0.f;
            #pragma unroll 8
            for (int i = 0; i < 128; ++i) acc += W1[j * 128 + i] * Wv[i];
            u1[j] = acc;
        }
        __syncthreads();
        if (tid == 0) {
            float s = 0.f;
            for (int i = 0; i < 128; ++i) s += sm[i];
            bqk[0] = s;
        }
    } else if (bid <= 16) {
        const int base = (bid - 1) * 1024 + tid * 4;
        const float4 w = *reinterpret_cast<const float4*>(W2 + base);
        const float f[4] = {w.x, w.y, w.z, w.w};
        u16 o[4];
        #pragma unroll
        for (int e = 0; e < 4; ++e) {
            __hip_bfloat16 hb = __float2bfloat16(f[e]);
            __builtin_memcpy(&o[e], &hb, 2);
        }
        *reinterpret_cast<ushort4*>(W2bf + base) = make_ushort4(o[0], o[1], o[2], o[3]);
    } else {
        const int i = (bid - 17) * 256 + tid;
        if (i < G) asum[i] = 0.f;
    }
}

// Block = 256 threads = 8 half-waves; each half-wave (32 lanes) processes 16
// consecutive rows (block covers 128 nodes). Then an in-LDS segmented
// reduction (batch is sorted) does ~2-3 atomicAdds per block instead of 128.
__global__ __launch_bounds__(256) void attn_kernel(
    const float* __restrict__ ns, const int* __restrict__ batch,
    const float* __restrict__ spin, const float* __restrict__ wqk,
    const float* __restrict__ bqk, float* __restrict__ attn,
    float* __restrict__ asum, int N)
{
    __shared__ float sattn[128];
    __shared__ int   sbatch[128];
    const int tid = threadIdx.x;
    const int l32 = tid & 31;
    const int hw  = tid >> 5;            // half-wave id 0..7
    const int rbase = blockIdx.x * 128 + hw * 16;

    const float4 wv = *reinterpret_cast<const float4*>(wqk + l32 * 4);
    const float bq0 = bqk[0];

    #pragma unroll 8
    for (int k = 0; k < 16; ++k) {
        const int n = rbase + k;
        float p = 0.f;
        if (n < N) {
            const float4 x = *reinterpret_cast<const float4*>(ns + (size_t)n * 128 + l32 * 4);
            p = x.x * wv.x + x.y * wv.y + x.z * wv.z + x.w * wv.w;
        }
        #pragma unroll
        for (int off = 16; off > 0; off >>= 1) p += __shfl_xor(p, off, 64);
        if (l32 == 0) {
            float a = 0.f;
            int g = -1;
            if (n < N) {
                g = batch[n];
                const float sp = spin[g];
                const float ratio = sp / fmaxf(sp, 1.0f);
                const float xx = (p + bq0) * ratio * 0.08838834764831845f;
                a = softplus_f(xx);
                attn[n] = a;
            }
            sattn[hw * 16 + k]  = a;
            sbatch[hw * 16 + k] = g;
        }
    }
    __syncthreads();

    // segmented reduction over the block's 128 nodes (sorted batch)
    if (tid < 128) {
        const int g = sbatch[tid];
        if (g >= 0 && (tid == 0 || sbatch[tid - 1] != g)) {
            float s = 0.f;
            int j = tid;
            while (j < 128 && sbatch[j] == g) { s += sattn[j]; ++j; }
            atomicAdd(&asum[g], s);
        }
    }
}

// 64 nodes per block. c + h1 (bf16) in LDS, then per-wave 16x128 MFMA GEMM
// against L1-resident W2bf, fused epilogue out = ns + c*Wv + silu(acc+b2).
__global__ __launch_bounds__(256) void main_kernel(
    const float* __restrict__ ns, const int* __restrict__ batch,
    const float* __restrict__ spin, const float* __restrict__ Wv,
    const float* __restrict__ b1, const float* __restrict__ b2,
    const float* __restrict__ u1, const float* __restrict__ attn,
    const float* __restrict__ asum, const u16* __restrict__ W2bf,
    float* __restrict__ out, int N)
{
    __shared__ float c_lds[64];
    __shared__ __align__(16) u16 h1[64][136];   // pad 128->136 (272B rows) vs bank conflicts
    const int tid = threadIdx.x;
    const int n0 = blockIdx.x * 64;

    if (tid < 64) {
        const int n = n0 + tid;
        float c = 0.f;
        if (n < N) {
            const int g = batch[n];
            c = attn[n] * spin[g] / asum[g];
        }
        c_lds[tid] = c;
    }
    __syncthreads();

    // h1[node][j] = silu(c[node]*u1[j] + b1[j]), bf16. Thread: 4 j's x 8 nodes.
    {
        const int j0 = (tid & 31) * 4;
        const int nb = (tid >> 5) * 8;
        const float4 u1v = *reinterpret_cast<const float4*>(u1 + j0);
        const float4 b1v = *reinterpret_cast<const float4*>(b1 + j0);
        const float uu[4] = {u1v.x, u1v.y, u1v.z, u1v.w};
        const float bb[4] = {b1v.x, b1v.y, b1v.z, b1v.w};
        #pragma unroll
        for (int e = 0; e < 8; ++e) {
            const int node = nb + e;
            const float c = c_lds[node];
            u16 pk[4];
            #pragma unroll
            for (int q = 0; q < 4; ++q) {
                const float hv = silu_f(c * uu[q] + bb[q]);
                __hip_bfloat16 hb = __float2bfloat16(hv);
                __builtin_memcpy(&pk[q], &hb, 2);
            }
            *reinterpret_cast<ushort4*>(&h1[node][j0]) =
                make_ushort4(pk[0], pk[1], pk[2], pk[3]);
        }
    }
    __syncthreads();

    const int lane = tid & 63;
    const int w = tid >> 6;
    const int r16 = lane & 15;
    const int g4 = lane >> 4;
    const int nw0 = w * 16;   // wave's 16-node sub-tile

    // A-frags: lane holds h1[row = r16][k = kt*32 + g4*8 + e]
    short8 a[4];
    const u16* arow = &h1[nw0 + r16][g4 * 8];
    #pragma unroll
    for (int kt = 0; kt < 4; ++kt)
        a[kt] = *reinterpret_cast<const short8*>(arow + kt * 32);

    #pragma unroll
    for (int ct = 0; ct < 8; ++ct) {
        const int i = ct * 16 + r16;
        const u16* brow = W2bf + i * 128 + g4 * 8;   // B[k][col=i] = W2[i][k]
        f32x4 acc = {0.f, 0.f, 0.f, 0.f};
        #pragma unroll
        for (int kt = 0; kt < 4; ++kt) {
            const short8 b = *reinterpret_cast<const short8*>(brow + kt * 32);
            acc = __builtin_amdgcn_mfma_f32_16x16x32_bf16(a[kt], b, acc, 0, 0, 0);
        }
        const float b2i = b2[i];
        const float wvi = Wv[i];
        #pragma unroll
        for (int r = 0; r < 4; ++r) {
            const int nl = nw0 + g4 * 4 + r;          // D: row=(lane>>4)*4+reg, col=lane&15
            const int n = n0 + nl;
            if (n < N) {
                const float h2v = silu_f(acc[r] + b2i);
                out[(size_t)n * 128 + i] = ns[(size_t)n * 128 + i] + c_lds[nl] * wvi + h2v;
            }
        }
    }
}

extern "C" void kernel_launch(void* const* d_in, const int* in_sizes, int n_in,
                              void* d_out, int out_size, void* d_ws, size_t ws_size,
                              hipStream_t stream) {
    (void)n_in; (void)out_size; (void)ws_size;
    const float* ns    = (const float*)d_in[0];
    const int*   batch = (const int*)d_in[1];
    const float* spin  = (const float*)d_in[2];
    const float* Wq    = (const float*)d_in[3];
    const float* bq    = (const float*)d_in[4];
    const float* Wk    = (const float*)d_in[5];
    const float* Wv    = (const float*)d_in[6];
    const float* W1    = (const float*)d_in[7];
    const float* b1    = (const float*)d_in[8];
    const float* W2    = (const float*)d_in[9];
    const float* b2    = (const float*)d_in[10];
    float* out = (float*)d_out;

    const int N = in_sizes[0] / 128;
    const int G = in_sizes[2];

    float* ws = (float*)d_ws;
    size_t o = 0;
    float* asum = ws + o; o += (size_t)((G + 63) & ~63);
    float* attn = ws + o; o += (size_t)((N + 63) & ~63);
    float* wqk  = ws + o; o += 128;
    float* u1   = ws + o; o += 128;
    float* bqk  = ws + o; o += 64;
    u16*   W2bf = (u16*)(ws + o);   // 16384 u16 = 32 KB

    const int zeroBlocks = (G + 255) / 256;
    prep_kernel<<<dim3(17 + zeroBlocks), dim3(256), 0, stream>>>(
        Wq, bq, Wk, Wv, W1, W2, wqk, u1, bqk, W2bf, asum, G);
    attn_kernel<<<dim3((N + 127) / 128), dim3(256), 0, stream>>>(
        ns, batch, spin, wqk, bqk, attn, asum, N);
    main_kernel<<<dim3((N + 63) / 64), dim3(256), 0, stream>>>(
        ns, batch, spin, Wv, b1, b2, u1, attn, asum, W2bf, out, N);
}

// Round 5
// 274.618 us; speedup vs baseline: 1.3597x; 1.0764x over previous
//
#include <hip/hip_runtime.h>
#include <hip/hip_bf16.h>

typedef unsigned short u16;
typedef __attribute__((ext_vector_type(8))) short short8;
typedef __attribute__((ext_vector_type(4))) float f32x4;

__device__ __forceinline__ float silu_f(float x) { return x / (1.0f + __expf(-x)); }
__device__ __forceinline__ float softplus_f(float x) {
    return (x > 20.0f) ? x : log1pf(__expf(x));
}

// Block 0: wqk[j]=sum_i Wq[i][j]*Wk[i], u1[j]=sum_i W1[j][i]*Wv[i], bqk=bq.Wk
// Blocks 1..16: W2 -> bf16 copy
// Blocks 17..: zero asum
__global__ __launch_bounds__(256) void prep_kernel(
    const float* __restrict__ Wq, const float* __restrict__ bq,
    const float* __restrict__ Wk, const float* __restrict__ Wv,
    const float* __restrict__ W1, const float* __restrict__ W2,
    float* __restrict__ wqk, float* __restrict__ u1, float* __restrict__ bqk,
    u16* __restrict__ W2bf, float* __restrict__ asum, int G)
{
    const int tid = threadIdx.x;
    const int bid = blockIdx.x;
    if (bid == 0) {
        __shared__ float sm[128];
        if (tid < 128) {
            float acc = 0.f;
            #pragma unroll 8
            for (int i = 0; i < 128; ++i) acc += Wq[i * 128 + tid] * Wk[i];
            wqk[tid] = acc;
            sm[tid] = bq[tid] * Wk[tid];
        } else {
            const int j = tid - 128;
            float acc = 0.f;
            #pragma unroll 8
            for (int i = 0; i < 128; ++i) acc += W1[j * 128 + i] * Wv[i];
            u1[j] = acc;
        }
        __syncthreads();
        if (tid == 0) {
            float s = 0.f;
            for (int i = 0; i < 128; ++i) s += sm[i];
            bqk[0] = s;
        }
    } else if (bid <= 16) {
        const int base = (bid - 1) * 1024 + tid * 4;
        const float4 w = *reinterpret_cast<const float4*>(W2 + base);
        const float f[4] = {w.x, w.y, w.z, w.w};
        u16 o[4];
        #pragma unroll
        for (int e = 0; e < 4; ++e) {
            __hip_bfloat16 hb = __float2bfloat16(f[e]);
            __builtin_memcpy(&o[e], &hb, 2);
        }
        *reinterpret_cast<ushort4*>(W2bf + base) = make_ushort4(o[0], o[1], o[2], o[3]);
    } else {
        const int i = (bid - 17) * 256 + tid;
        if (i < G) asum[i] = 0.f;
    }
}

// Block = 256 threads; 8 half-waves x 16 rows = 128 nodes/block.
// Phase 2: parallel LDS-slot segmented sum (batch sorted -> g-g0 in [0,127]),
// then <=128 parallel global atomics of per-block partial sums.
__global__ __launch_bounds__(256) void attn_kernel(
    const float* __restrict__ ns, const int* __restrict__ batch,
    const float* __restrict__ spin, const float* __restrict__ wqk,
    const float* __restrict__ bqk, float* __restrict__ attn,
    float* __restrict__ asum, int N)
{
    __shared__ float sattn[128];
    __shared__ int   sbatch[128];
    __shared__ float slots[128];
    const int tid = threadIdx.x;
    const int l32 = tid & 31;
    const int hw  = tid >> 5;            // half-wave id 0..7
    const int rbase = blockIdx.x * 128 + hw * 16;

    const float4 wv = *reinterpret_cast<const float4*>(wqk + l32 * 4);
    const float bq0 = bqk[0];
    if (tid < 128) slots[tid] = 0.f;

    #pragma unroll 8
    for (int k = 0; k < 16; ++k) {
        const int n = rbase + k;
        float p = 0.f;
        if (n < N) {
            const float4 x = *reinterpret_cast<const float4*>(ns + (size_t)n * 128 + l32 * 4);
            p = x.x * wv.x + x.y * wv.y + x.z * wv.z + x.w * wv.w;
        }
        #pragma unroll
        for (int off = 16; off > 0; off >>= 1) p += __shfl_xor(p, off, 64);
        if (l32 == 0) {
            float a = 0.f;
            int g = -1;
            if (n < N) {
                g = batch[n];
                const float sp = spin[g];
                const float ratio = sp / fmaxf(sp, 1.0f);
                const float xx = (p + bq0) * ratio * 0.08838834764831845f;
                a = softplus_f(xx);
                attn[n] = a;
            }
            sattn[hw * 16 + k]  = a;
            sbatch[hw * 16 + k] = g;
        }
    }
    __syncthreads();

    const int g0 = sbatch[0];            // block's first (minimum) graph id
    if (tid < 128) {
        const int g = sbatch[tid];
        if (g >= 0) atomicAdd(&slots[g - g0], sattn[tid]);   // LDS atomic
    }
    __syncthreads();
    if (tid < 128) {
        const float s = slots[tid];
        if (s != 0.f) atomicAdd(&asum[g0 + tid], s);         // global atomic
    }
}

// 64 nodes/block. Phase A: c + h1(bf16) in LDS -> MFMA A-frags.
// Phase B: per-wave 16x128 MFMA vs W2bf (L2-resident), stage
//   c*Wv + silu(acc+b2) into f32 LDS tile (overlaid on h1).
// Phase C: coalesced float4 pass  out = ns + hout  (1KB/instruction).
__global__ __launch_bounds__(256) void main_kernel(
    const float* __restrict__ ns, const int* __restrict__ batch,
    const float* __restrict__ spin, const float* __restrict__ Wv,
    const float* __restrict__ b1, const float* __restrict__ b2,
    const float* __restrict__ u1, const float* __restrict__ attn,
    const float* __restrict__ asum, const u16* __restrict__ W2bf,
    float* __restrict__ out, int N)
{
    __shared__ float c_lds[64];
    __shared__ __align__(16) unsigned char smem[64 * 132 * 4];  // 33.8 KB overlay
    u16   (*h1)[136]   = reinterpret_cast<u16(*)[136]>(smem);   // phase A view
    float (*hout)[132] = reinterpret_cast<float(*)[132]>(smem); // phase B/C view
    const int tid = threadIdx.x;
    const int n0 = blockIdx.x * 64;

    if (tid < 64) {
        const int n = n0 + tid;
        float c = 0.f;
        if (n < N) {
            const int g = batch[n];
            c = attn[n] * spin[g] / asum[g];
        }
        c_lds[tid] = c;
    }
    __syncthreads();

    // h1[node][j] = silu(c[node]*u1[j] + b1[j]), bf16. Thread: 4 j's x 8 nodes.
    {
        const int j0 = (tid & 31) * 4;
        const int nb = (tid >> 5) * 8;
        const float4 u1v = *reinterpret_cast<const float4*>(u1 + j0);
        const float4 b1v = *reinterpret_cast<const float4*>(b1 + j0);
        const float uu[4] = {u1v.x, u1v.y, u1v.z, u1v.w};
        const float bb[4] = {b1v.x, b1v.y, b1v.z, b1v.w};
        #pragma unroll
        for (int e = 0; e < 8; ++e) {
            const int node = nb + e;
            const float c = c_lds[node];
            u16 pk[4];
            #pragma unroll
            for (int q = 0; q < 4; ++q) {
                const float hv = silu_f(c * uu[q] + bb[q]);
                __hip_bfloat16 hb = __float2bfloat16(hv);
                __builtin_memcpy(&pk[q], &hb, 2);
            }
            *reinterpret_cast<ushort4*>(&h1[node][j0]) =
                make_ushort4(pk[0], pk[1], pk[2], pk[3]);
        }
    }
    __syncthreads();

    const int lane = tid & 63;
    const int w = tid >> 6;
    const int r16 = lane & 15;
    const int g4 = lane >> 4;
    const int nw0 = w * 16;   // wave's 16-node sub-tile

    // A-frags: lane holds h1[row = r16][k = kt*32 + g4*8 + e]
    short8 a[4];
    const u16* arow = &h1[nw0 + r16][g4 * 8];
    #pragma unroll
    for (int kt = 0; kt < 4; ++kt)
        a[kt] = *reinterpret_cast<const short8*>(arow + kt * 32);
    __syncthreads();   // all h1 reads done before hout overwrites the overlay

    const float c_mine[4] = { c_lds[nw0 + g4 * 4 + 0], c_lds[nw0 + g4 * 4 + 1],
                              c_lds[nw0 + g4 * 4 + 2], c_lds[nw0 + g4 * 4 + 3] };

    #pragma unroll
    for (int ct = 0; ct < 8; ++ct) {
        const int i = ct * 16 + r16;
        const u16* brow = W2bf + i * 128 + g4 * 8;   // B[k][col=i] = W2[i][k]
        f32x4 acc = {0.f, 0.f, 0.f, 0.f};
        #pragma unroll
        for (int kt = 0; kt < 4; ++kt) {
            const short8 b = *reinterpret_cast<const short8*>(brow + kt * 32);
            acc = __builtin_amdgcn_mfma_f32_16x16x32_bf16(a[kt], b, acc, 0, 0, 0);
        }
        const float b2i = b2[i];
        const float wvi = Wv[i];
        #pragma unroll
        for (int r = 0; r < 4; ++r) {
            const int nl = nw0 + g4 * 4 + r;          // D: row=(lane>>4)*4+reg, col=lane&15
            hout[nl][i] = c_mine[r] * wvi + silu_f(acc[r] + b2i);
        }
    }
    __syncthreads();

    // Phase C: out[n0+row][col] = ns[...] + hout[row][col], coalesced float4.
    #pragma unroll
    for (int e = 0; e < 8; ++e) {
        const int flat = e * 1024 + tid * 4;   // 64*128 floats total
        const int row = flat >> 7;
        const int col = flat & 127;
        const int n = n0 + row;
        if (n < N) {
            const float4 hv = *reinterpret_cast<const float4*>(&hout[row][col]);
            const float4 nv = *reinterpret_cast<const float4*>(ns + (size_t)n * 128 + col);
            float4 ov;
            ov.x = nv.x + hv.x; ov.y = nv.y + hv.y;
            ov.z = nv.z + hv.z; ov.w = nv.w + hv.w;
            *reinterpret_cast<float4*>(out + (size_t)n * 128 + col) = ov;
        }
    }
}

extern "C" void kernel_launch(void* const* d_in, const int* in_sizes, int n_in,
                              void* d_out, int out_size, void* d_ws, size_t ws_size,
                              hipStream_t stream) {
    (void)n_in; (void)out_size; (void)ws_size;
    const float* ns    = (const float*)d_in[0];
    const int*   batch = (const int*)d_in[1];
    const float* spin  = (const float*)d_in[2];
    const float* Wq    = (const float*)d_in[3];
    const float* bq    = (const float*)d_in[4];
    const float* Wk    = (const float*)d_in[5];
    const float* Wv    = (const float*)d_in[6];
    const float* W1    = (const float*)d_in[7];
    const float* b1    = (const float*)d_in[8];
    const float* W2    = (const float*)d_in[9];
    const float* b2    = (const float*)d_in[10];
    float* out = (float*)d_out;

    const int N = in_sizes[0] / 128;
    const int G = in_sizes[2];

    float* ws = (float*)d_ws;
    size_t o = 0;
    float* asum = ws + o; o += (size_t)((G + 63) & ~63);
    float* attn = ws + o; o += (size_t)((N + 63) & ~63);
    float* wqk  = ws + o; o += 128;
    float* u1   = ws + o; o += 128;
    float* bqk  = ws + o; o += 64;
    u16*   W2bf = (u16*)(ws + o);   // 16384 u16 = 32 KB

    const int zeroBlocks = (G + 255) / 256;
    prep_kernel<<<dim3(17 + zeroBlocks), dim3(256), 0, stream>>>(
        Wq, bq, Wk, Wv, W1, W2, wqk, u1, bqk, W2bf, asum, G);
    attn_kernel<<<dim3((N + 127) / 128), dim3(256), 0, stream>>>(
        ns, batch, spin, wqk, bqk, attn, asum, N);
    main_kernel<<<dim3((N + 63) / 64), dim3(256), 0, stream>>>(
        ns, batch, spin, Wv, b1, b2, u1, attn, asum, W2bf, out, N);
}